// Round 1
// baseline (1303.168 us; speedup 1.0000x reference)
//
#include <hip/hip_runtime.h>
#include <math.h>

// GraphGPS GatedGCN stack, fused single cooperative kernel.
// 256 graphs -> 256 blocks (1/CU), 512 threads (8 waves).
// h[32][70] in LDS; e[256][70] row-per-(thread-pair) in registers.
// BN batch stats via global fp32 atomics + grid barrier (1 per layer).

#define TPB 512
#define NBLK 256
#define DD 70
#define DP 72
#define NPG 32
#define EPG 256
#define NLAYERS 17
#define SPL 280           // stats floats per layer: xsum70 xsq70 esum70 esq70
#define EPS_AGG 1e-6f
#define EPS_BN 1e-5f
#define EPS_LN 1e-5f

// LDS layout (floats): h,Ax,Bx,Dx,Ex [32][72] = 5*2304 ; wb 4*70*72=20160 (also sigbuf 256*72=18432) ; statl 576
// then ints: ioff[33], icur[32]; uchar: srcloc[256], dstloc[256], eidx[256]
#define SMEM_FLOATS (2304*5 + 20160 + 576)
#define SMEM_BYTES  (SMEM_FLOATS*4 + (33+32)*4 + 768 + 12)

struct GPSParams {
  const float* x; const int* ei; const float* ea;
  const float *wn, *bnn, *we, *web;
  const float *Aw[2], *Ab[2], *Bw[2], *Bb[2], *Cw[2], *Cb[2], *Dw[2], *Db[2], *Ew[2], *Eb[2];
  const float *gx[2], *bx[2], *ge[2], *gbe[2];
  const float *c1w, *c1b, *lng, *lnb, *c2w, *c2b;
  float* out; float* stats; unsigned* bar;
};

__device__ __forceinline__ void grid_sync(unsigned* cnt, unsigned* gen) {
  __syncthreads();
  if (threadIdx.x == 0) {
    unsigned g = __hip_atomic_load(gen, __ATOMIC_RELAXED, __HIP_MEMORY_SCOPE_AGENT);
    unsigned a = __hip_atomic_fetch_add(cnt, 1u, __ATOMIC_ACQ_REL, __HIP_MEMORY_SCOPE_AGENT);
    if (a == NBLK - 1u) {
      __hip_atomic_store(cnt, 0u, __ATOMIC_RELAXED, __HIP_MEMORY_SCOPE_AGENT);
      __hip_atomic_store(gen, g + 1u, __ATOMIC_RELEASE, __HIP_MEMORY_SCOPE_AGENT);
    } else {
      while (__hip_atomic_load(gen, __ATOMIC_ACQUIRE, __HIP_MEMORY_SCOPE_AGENT) == g)
        __builtin_amdgcn_s_sleep(2);
    }
  }
  __syncthreads();
}

__global__ void __launch_bounds__(TPB, 1) gps_kernel(GPSParams p) {
  extern __shared__ float smem[];
  float* sh_h  = smem;
  float* sh_Ax = smem + 2304;
  float* sh_Bx = smem + 2304*2;
  float* sh_Dx = smem + 2304*3;
  float* sh_Ex = smem + 2304*4;
  float* wb    = smem + 2304*5;       // weight slots / sigbuf
  float* statl = wb + 20160;          // 576 floats
  int*   ioff  = (int*)(statl + 576); // 33
  int*   icur  = ioff + 33;           // 32
  unsigned char* srcloc = (unsigned char*)(icur + 32);
  unsigned char* dstloc = srcloc + 256;
  unsigned char* eidxL  = dstloc + 256;

  const int tid  = threadIdx.x;
  const int g    = blockIdx.x;
  const int lane = tid & 63;
  const int wid  = tid >> 6;

  // edge roles: thread pair (2*eid, 2*eid+1) owns edge eid; ehalf = feature half
  const int eid = tid >> 1, ehalf = tid & 1;
  // node-GEMM roles: wave -> (kh, jh, matpair); lane -> (mat-in-pair, node)
  const int ng_kh = wid >> 2, ng_jh = (wid >> 1) & 1, ng_mp = wid & 1;
  const int ng_m = lane >> 5, ng_n = lane & 31;
  const int ng_slot = ng_mp*2 + ng_m;   // 0:A 1:B 2:D 3:E
  float* nbuf = (ng_slot==0) ? sh_Ax : (ng_slot==1) ? sh_Bx : (ng_slot==2) ? sh_Dx : sh_Ex;
  // gather items: (node, jquad), 576 items over 512 threads
  const int gn0 = tid / 18, gq0 = tid % 18;
  const bool has1 = (tid < 64);
  const int gn1 = (tid + 512) / 18, gq1 = (tid + 512) % 18;

  // ---------------- CSR build (once) ----------------
  if (tid < 32) icur[tid] = 0;
  __syncthreads();
  if (tid < 256) {
    int s = p.ei[g*EPG + tid]         - g*NPG;
    int d = p.ei[65536 + g*EPG + tid] - g*NPG;
    srcloc[tid] = (unsigned char)s;
    dstloc[tid] = (unsigned char)d;
    atomicAdd(&icur[d], 1);
  }
  __syncthreads();
  if (tid == 0) {
    int o = 0;
    for (int n = 0; n < 32; ++n) { ioff[n] = o; o += icur[n]; }
    ioff[32] = o;
  }
  __syncthreads();
  if (tid < 32) icur[tid] = ioff[tid];
  __syncthreads();
  if (tid < 256) {
    int d = dstloc[tid];
    int slot = atomicAdd(&icur[d], 1);
    eidxL[slot] = (unsigned char)tid;
  }

  // ---------------- init embeddings ----------------
  for (int i = tid; i < 32*DP; i += TPB) {
    int n = i / DP, j = i % DP;
    sh_h[i] = (j < DD) ? fmaf(p.x[g*NPG + n], p.wn[j], p.bnn[j]) : 0.f;
  }
  float ereg[35];
  {
    float eav = p.ea[g*EPG + eid];
    #pragma unroll
    for (int jj = 0; jj < 35; ++jj) {
      int j = ehalf*35 + jj;
      ereg[jj] = fmaf(eav, p.we[j], p.web[j]);
    }
  }
  __syncthreads();

  // ---------------- layer loop ----------------
  #pragma unroll 1
  for (int L = 0; L < NLAYERS; ++L) {
    const int s = (L == 0) ? 0 : 1;
    const float *Cw = p.Cw[s];
    const float *Awp = p.Aw[s], *Bwp = p.Bw[s], *Dwp = p.Dw[s], *Ewp = p.Ew[s];

    // S0: Cw -> wb slot0; bias-sum (Cb+Db+Eb) -> statl[432..501]
    for (int i = tid; i < 5040; i += TPB) {
      int k = i / DP, j = i % DP;
      wb[i] = (j < DD) ? Cw[k*DD + j] : 0.f;
    }
    if (tid < DD) statl[432 + tid] = p.Cb[s][tid] + p.Db[s][tid] + p.Eb[s][tid];
    __syncthreads();

    // S1: edge GEMM (Ce partial over own k-half), pair butterfly
    float acc[DP];
    #pragma unroll
    for (int j = 0; j < DP; ++j) acc[j] = 0.f;
    {
      const float* wr0 = wb + ehalf*35*DP;
      #pragma unroll
      for (int k = 0; k < 35; ++k) {
        float ek = ereg[k];
        const float4* wr = (const float4*)(wr0 + k*DP);
        #pragma unroll
        for (int jq = 0; jq < 18; ++jq) {
          float4 w4 = wr[jq];
          acc[jq*4+0] = fmaf(ek, w4.x, acc[jq*4+0]);
          acc[jq*4+1] = fmaf(ek, w4.y, acc[jq*4+1]);
          acc[jq*4+2] = fmaf(ek, w4.z, acc[jq*4+2]);
          acc[jq*4+3] = fmaf(ek, w4.w, acc[jq*4+3]);
        }
      }
    }
    #pragma unroll
    for (int j = 0; j < DD; ++j) acc[j] += __shfl_xor(acc[j], 1, 64);
    float enew[35];
    #pragma unroll
    for (int jj = 0; jj < 35; ++jj) enew[jj] = acc[ehalf*35 + jj];
    __syncthreads();  // done with Cw

    // S2: node weights A,B,D,E -> wb slots 0..3
    for (int i = tid; i < 20160; i += TPB) {
      int slot = i / 5040, r = i % 5040;
      int k = r / DP, j = r % DP;
      const float* wsrc = (slot == 0) ? Awp : (slot == 1) ? Bwp : (slot == 2) ? Dwp : Ewp;
      wb[i] = (j < DD) ? wsrc[k*DD + j] : 0.f;
    }
    __syncthreads();

    // S3: node GEMMs (k-half partials + combine)
    {
      float hreg[35];
      const float* hr = sh_h + ng_n*DP + ng_kh*35;
      #pragma unroll
      for (int k = 0; k < 35; ++k) hreg[k] = hr[k];
      float nacc[36];
      #pragma unroll
      for (int j2 = 0; j2 < 36; ++j2) nacc[j2] = 0.f;
      const float* wslot = wb + ng_slot*5040 + ng_kh*35*DP + ng_jh*36;
      #pragma unroll
      for (int k = 0; k < 35; ++k) {
        float hk = hreg[k];
        const float4* wr = (const float4*)(wslot + k*DP);
        #pragma unroll
        for (int jq = 0; jq < 9; ++jq) {
          float4 w4 = wr[jq];
          nacc[jq*4+0] = fmaf(hk, w4.x, nacc[jq*4+0]);
          nacc[jq*4+1] = fmaf(hk, w4.y, nacc[jq*4+1]);
          nacc[jq*4+2] = fmaf(hk, w4.z, nacc[jq*4+2]);
          nacc[jq*4+3] = fmaf(hk, w4.w, nacc[jq*4+3]);
        }
      }
      float* orow = nbuf + ng_n*DP + ng_jh*36;
      if (ng_kh == 0) {
        #pragma unroll
        for (int jq = 0; jq < 9; ++jq) {
          float4 v;
          v.x = nacc[jq*4+0]; v.y = nacc[jq*4+1]; v.z = nacc[jq*4+2]; v.w = nacc[jq*4+3];
          ((float4*)orow)[jq] = v;
        }
      }
      __syncthreads();
      if (ng_kh == 1) {
        const float* nb = (ng_slot==0) ? p.Ab[s] : (ng_slot==1) ? p.Bb[s] : (ng_slot==2) ? p.Db[s] : p.Eb[s];
        #pragma unroll
        for (int jq = 0; jq < 9; ++jq) {
          float4 q = ((const float4*)orow)[jq];
          int j0 = ng_jh*36 + jq*4;
          q.x += nacc[jq*4+0] + ((j0+0) < DD ? nb[j0+0] : 0.f);
          q.y += nacc[jq*4+1] + ((j0+1) < DD ? nb[j0+1] : 0.f);
          q.z += nacc[jq*4+2] + ((j0+2) < DD ? nb[j0+2] : 0.f);
          q.w += nacc[jq*4+3] + ((j0+3) < DD ? nb[j0+3] : 0.f);
          ((float4*)orow)[jq] = q;
        }
      }
      __syncthreads();
    }

    // S4: e_new = Ce + Dx[dst] + Ex[src] + (Cb+Db+Eb); stage to sigbuf (wb)
    {
      int dl = dstloc[eid], sl = srcloc[eid];
      const float* dxr = sh_Dx + dl*DP + ehalf*35;
      const float* exr = sh_Ex + sl*DP + ehalf*35;
      float* sr = wb + eid*DP + ehalf*35;
      #pragma unroll
      for (int jj = 0; jj < 35; ++jj) {
        int j = ehalf*35 + jj;
        enew[jj] += dxr[jj] + exr[jj] + statl[432 + j];
        sr[jj] = enew[jj];
      }
      if (ehalf == 1) { sr[35] = 0.f; sr[36] = 0.f; }  // pads j=70,71
    }
    __syncthreads();

    // S5: e-stats (block partial -> global atomics)
    if (tid < DD) {
      float sm = 0.f, sq = 0.f;
      for (int r = 0; r < 256; ++r) { float v = wb[r*DP + tid]; sm += v; sq = fmaf(v, v, sq); }
      atomicAdd(&p.stats[L*SPL + 140 + tid], sm);
      atomicAdd(&p.stats[L*SPL + 210 + tid], sq);
    }
    __syncthreads();

    // S6: overwrite sigbuf rows with sigmoid(e_new)
    {
      float* sr = wb + eid*DP + ehalf*35;
      #pragma unroll
      for (int jj = 0; jj < 35; ++jj)
        sr[jj] = 1.f / (1.f + __expf(-enew[jj]));
    }
    __syncthreads();

    // S7: gather (CSR) + x_new = Ax + num/den, in place into Ax
    {
      auto gather_item = [&](int n, int jq) {
        int jo = jq*4;
        float4 nm; nm.x = nm.y = nm.z = nm.w = 0.f;
        float4 dn; dn.x = dn.y = dn.z = dn.w = 0.f;
        int pb = ioff[n], pe = ioff[n+1];
        for (int pp = pb; pp < pe; ++pp) {
          int e2 = eidxL[pp];
          float4 sg = *(const float4*)(wb + e2*DP + jo);
          float4 b4 = *(const float4*)(sh_Bx + (int)srcloc[e2]*DP + jo);
          nm.x = fmaf(sg.x, b4.x, nm.x); nm.y = fmaf(sg.y, b4.y, nm.y);
          nm.z = fmaf(sg.z, b4.z, nm.z); nm.w = fmaf(sg.w, b4.w, nm.w);
          dn.x += sg.x; dn.y += sg.y; dn.z += sg.z; dn.w += sg.w;
        }
        float* axr = sh_Ax + n*DP + jo;
        float4 ax = *(const float4*)axr;
        ax.x += nm.x / (dn.x + EPS_AGG);
        ax.y += nm.y / (dn.y + EPS_AGG);
        ax.z += nm.z / (dn.z + EPS_AGG);
        ax.w += nm.w / (dn.w + EPS_AGG);
        *(float4*)axr = ax;
      };
      gather_item(gn0, gq0);
      if (has1) gather_item(gn1, gq1);
    }
    __syncthreads();

    // S8: x-stats
    if (tid < DD) {
      float sm = 0.f, sq = 0.f;
      for (int r = 0; r < 32; ++r) { float v = sh_Ax[r*DP + tid]; sm += v; sq = fmaf(v, v, sq); }
      atomicAdd(&p.stats[L*SPL + tid], sm);
      atomicAdd(&p.stats[L*SPL + 70 + tid], sq);
    }

    // S9: global barrier (all blocks' stats complete)
    grid_sync(p.bar, p.bar + 1);

    // S10: load stats, compute scale/shift
    if (tid < SPL)
      statl[288 + tid] = __hip_atomic_load(&p.stats[L*SPL + tid], __ATOMIC_RELAXED, __HIP_MEMORY_SCOPE_AGENT);
    __syncthreads();
    if (tid < 70) {
      float mean = statl[288 + tid] * (1.f/8192.f);
      float var  = statl[288 + 70 + tid] * (1.f/8192.f) - mean*mean;
      float sc = p.gx[s][tid] * rsqrtf(var + EPS_BN);
      statl[tid]      = sc;
      statl[72 + tid] = fmaf(-mean, sc, p.bx[s][tid]);
    } else if (tid < 140) {
      int j = tid - 70;
      float mean = statl[288 + 140 + j] * (1.f/65536.f);
      float var  = statl[288 + 210 + j] * (1.f/65536.f) - mean*mean;
      float sc = p.ge[s][j] * rsqrtf(var + EPS_BN);
      statl[144 + j] = sc;
      statl[216 + j] = fmaf(-mean, sc, p.gbe[s][j]);
    } else if (tid < 148) {
      int idx = tid - 140;
      statl[(idx >> 1)*72 + 70 + (idx & 1)] = 0.f;  // zero pads of sc/sh arrays
    }
    __syncthreads();

    // S11: apply BN+ReLU+residual to h and e
    {
      auto apply_h = [&](int n, int jq) {
        int jo = jq*4;
        float4 sc4 = *(const float4*)(statl + jo);
        float4 sb4 = *(const float4*)(statl + 72 + jo);
        float4 xn  = *(const float4*)(sh_Ax + n*DP + jo);
        float* hp = sh_h + n*DP + jo;
        float4 h4 = *(const float4*)hp;
        h4.x += fmaxf(fmaf(xn.x, sc4.x, sb4.x), 0.f);
        h4.y += fmaxf(fmaf(xn.y, sc4.y, sb4.y), 0.f);
        h4.z += fmaxf(fmaf(xn.z, sc4.z, sb4.z), 0.f);
        h4.w += fmaxf(fmaf(xn.w, sc4.w, sb4.w), 0.f);
        *(float4*)hp = h4;
      };
      apply_h(gn0, gq0);
      if (has1) apply_h(gn1, gq1);
      #pragma unroll
      for (int jj = 0; jj < 35; ++jj) {
        int j = ehalf*35 + jj;
        float v = fmaf(enew[jj], statl[144 + j], statl[216 + j]);
        ereg[jj] += fmaxf(v, 0.f);
      }
    }
    __syncthreads();
  }

  // ---------------- readout: pool + fc1 + LN + fc2 ----------------
  if (tid < DD) {
    float mx = -3.4e38f, sm = 0.f;
    for (int r = 0; r < 32; ++r) { float v = sh_h[r*DP + tid]; mx = fmaxf(mx, v); sm += v; }
    statl[tid]      = mx;             // gmp
    statl[72 + tid] = sm * (1.f/32.f);// gap
  }
  __syncthreads();
  if (tid < 256) {
    float a = p.c1b[tid];
    for (int k = 0; k < 70; ++k) a = fmaf(statl[k],      p.c1w[k*256 + tid], a);
    for (int k = 0; k < 70; ++k) a = fmaf(statl[72 + k], p.c1w[(70 + k)*256 + tid], a);
    sh_Ax[tid] = fmaxf(a, 0.f);
  }
  __syncthreads();
  if (tid == 0) {
    float sm = 0.f, sq = 0.f;
    for (int k = 0; k < 256; ++k) { float v = sh_Ax[k]; sm += v; sq = fmaf(v, v, sq); }
    float mean = sm * (1.f/256.f);
    float var  = sq * (1.f/256.f) - mean*mean;
    statl[300] = mean;
    statl[301] = rsqrtf(var + EPS_LN);
  }
  __syncthreads();
  if (tid < 256) {
    float v = (sh_Ax[tid] - statl[300]) * statl[301];
    sh_Bx[tid] = fmaf(v, p.lng[tid], p.lnb[tid]);
  }
  __syncthreads();
  if (tid < 10) {
    float a = p.c2b[tid];
    for (int k = 0; k < 256; ++k) a = fmaf(sh_Bx[k], p.c2w[k*10 + tid], a);
    p.out[g*10 + tid] = a;
  }
}

extern "C" void kernel_launch(void* const* d_in, const int* in_sizes, int n_in,
                              void* d_out, int out_size, void* d_ws, size_t ws_size,
                              hipStream_t stream) {
  (void)in_sizes; (void)n_in; (void)out_size; (void)ws_size;
  GPSParams p;
  p.x   = (const float*)d_in[0];
  p.ei  = (const int*)  d_in[1];
  p.ea  = (const float*)d_in[2];
  // d_in[3] = batch_index (layout known: 32 nodes/graph, contiguous)
  p.wn  = (const float*)d_in[4];  p.bnn = (const float*)d_in[5];
  p.we  = (const float*)d_in[6];  p.web = (const float*)d_in[7];
  int i = 8;
  for (int s = 0; s < 2; ++s) {
    p.Aw[s] = (const float*)d_in[i++]; p.Ab[s] = (const float*)d_in[i++];
    p.Bw[s] = (const float*)d_in[i++]; p.Bb[s] = (const float*)d_in[i++];
    p.Cw[s] = (const float*)d_in[i++]; p.Cb[s] = (const float*)d_in[i++];
    p.Dw[s] = (const float*)d_in[i++]; p.Db[s] = (const float*)d_in[i++];
    p.Ew[s] = (const float*)d_in[i++]; p.Eb[s] = (const float*)d_in[i++];
    p.gx[s] = (const float*)d_in[i++]; p.bx[s] = (const float*)d_in[i++];
    p.ge[s] = (const float*)d_in[i++]; p.gbe[s] = (const float*)d_in[i++];
  }
  p.c1w = (const float*)d_in[36]; p.c1b = (const float*)d_in[37];
  p.lng = (const float*)d_in[38]; p.lnb = (const float*)d_in[39];
  p.c2w = (const float*)d_in[40]; p.c2b = (const float*)d_in[41];
  p.out = (float*)d_out;
  p.bar = (unsigned*)d_ws;
  p.stats = (float*)((char*)d_ws + 256);

  // zero barrier + stats region each call (ws is not re-poisoned between replays)
  hipMemsetAsync(d_ws, 0, 256 + NLAYERS*SPL*4, stream);

  static int attr_set = 0;
  hipFuncSetAttribute((const void*)gps_kernel,
                      hipFuncAttributeMaxDynamicSharedMemorySize, SMEM_BYTES);
  (void)attr_set;

  void* args[] = { (void*)&p };
  hipError_t err = hipLaunchCooperativeKernel((const void*)gps_kernel,
                                              dim3(NBLK), dim3(TPB),
                                              args, SMEM_BYTES, stream);
  if (err != hipSuccess) {
    // fallback: plain launch (all 256 blocks are co-resident at 1 block/CU anyway)
    gps_kernel<<<dim3(NBLK), dim3(TPB), SMEM_BYTES, stream>>>(p);
  }
}